// Round 16
// baseline (392.418 us; speedup 1.0000x reference)
//
#include <hip/hip_runtime.h>
#include <hip/hip_fp16.h>
#include <stdint.h>

#define NROWS 8192   // B*S
#define HDIM  128
#define KSUB  8
#define NC    4096
#define DSUB  16
#define OUTD  6

#define FB_TAU 6e-5f                // fallback margin; split-fp16 distance error bound ~1.5e-5
#define DOTSCALE (-2.0f / 4096.0f)  // undo x*256, c*16 scaling; exact pow2

typedef _Float16 f16x8 __attribute__((ext_vector_type(8)));
typedef float    f32x4 __attribute__((ext_vector_type(4)));

// ws layout (bytes):
#define XK_OFF 0u            // xk:   [KSUB][NROWS][DSUB] fp32, 4 MiB
#define PK_OFF 4194304u      // pk:   [4 splits][NROWS][KSUB] u64, 2 MiB
#define DN_OFF 6291456u      // done: 64 u32 counters (zeroed via hipMemsetAsync each launch)

// LDS plan (one 50176-B arena + 2 scalars):
//   region1 @0     : h1s[64][132] fp32 (33792 B)   -- MLP phase
//                    scan: cs 8 KiB @0, cnL 4 KiB @8192
//                    finish: codes_s 4 KiB @0, wl_s 4 KiB @4096
//   x2s @33792     : [128][16] fp32 (8192 B)        -- h2 slice (persists MLP->A-frags)
//   w2k @41984     : [128][16] fp32 (8192 B)        -- W2 k-slice
#define SM_TOTAL 50176
#define X2_OFF_B 33792
#define W2_OFF_B 41984

__global__ __launch_bounds__(256, 3) void fused_kernel(
    const float* __restrict__ z, const float* __restrict__ W1, const float* __restrict__ b1,
    const float* __restrict__ W2, const float* __restrict__ b2,
    const float* __restrict__ ce, const float* __restrict__ W3, const float* __restrict__ b3,
    float* __restrict__ xk, unsigned long long* __restrict__ pk,
    unsigned int* __restrict__ done, float* __restrict__ out)
{
    __shared__ __align__(16) char smem[SM_TOTAL];
    float* h1s = (float*)smem;                    // [64][132]
    float* x2s = (float*)(smem + X2_OFF_B);       // [128][16]
    float* w2k = (float*)(smem + W2_OFF_B);       // [128][16]
    f16x8* cs  = (f16x8*)smem;                    // [8*64] scan tiles
    float* cnL = (float*)(smem + 8192);           // [1024] scan norms
    int* codes_s = (int*)smem;                    // [1024] finish
    int* wl_s    = (int*)(smem + 4096);           // [1024] finish
    __shared__ int wcnt;
    __shared__ int isLast;

    const int t = threadIdx.x;
    const int lane = t & 63;
    const int wid  = t >> 6;
    const int bx = blockIdx.x;                 // 0..63 (128-row group)
    const int k  = blockIdx.y;                 // 0..7
    const int cz = blockIdx.z;                 // 0..3
    const int row0 = bx * 128;

    // ---- stage W2 k-slice [128][16] (8 KiB) ----
    #pragma unroll
    for (int q = 0; q < 8; ++q) {
        const int e = q * 256 + t;
        w2k[e] = W2[(e >> 4) * HDIM + k * DSUB + (e & 15)];
    }

    // ---- MLP in two 64-row halves (bit-identical fma chains to rounds 1-15) ----
    for (int h = 0; h < 2; ++h) {
        __syncthreads();   // w2k staged (h=0) / previous half's h1s readers done (h=1)
        #pragma unroll
        for (int q = 0; q < 32; ++q) {         // h1 = relu(z@W1 + b1), 64 rows
            const int e = q * 256 + t;
            const int r = e >> 7, j = e & 127;
            const int n = row0 + h * 64 + r;
            float a = b1[j];
            a = fmaf(z[n * 3 + 0], W1[0 * HDIM + j], a);
            a = fmaf(z[n * 3 + 1], W1[1 * HDIM + j], a);
            a = fmaf(z[n * 3 + 2], W1[2 * HDIM + j], a);
            h1s[r * 132 + j] = fmaxf(a, 0.f);
        }
        __syncthreads();
        // h2 slice: thread -> row r = t>>2, cols c0..c0+3 of this k's 16
        {
            const int r  = t >> 2;
            const int c0 = (t & 3) * 4;
            float a0 = 0.f, a1 = 0.f, a2 = 0.f, a3 = 0.f;
            for (int k4 = 0; k4 < HDIM; k4 += 4) {
                const float4 hh = *(const float4*)&h1s[r * 132 + k4];
                const float* wp = &w2k[k4 * 16 + c0];  // broadcast reads (4 addrs/wave)
                a0 = fmaf(hh.x, wp[0],  a0); a1 = fmaf(hh.x, wp[1],  a1);
                a2 = fmaf(hh.x, wp[2],  a2); a3 = fmaf(hh.x, wp[3],  a3);
                a0 = fmaf(hh.y, wp[16], a0); a1 = fmaf(hh.y, wp[17], a1);
                a2 = fmaf(hh.y, wp[18], a2); a3 = fmaf(hh.y, wp[19], a3);
                a0 = fmaf(hh.z, wp[32], a0); a1 = fmaf(hh.z, wp[33], a1);
                a2 = fmaf(hh.z, wp[34], a2); a3 = fmaf(hh.z, wp[35], a3);
                a0 = fmaf(hh.w, wp[48], a0); a1 = fmaf(hh.w, wp[49], a1);
                a2 = fmaf(hh.w, wp[50], a2); a3 = fmaf(hh.w, wp[51], a3);
            }
            const float4 bb = *(const float4*)&b2[k * DSUB + c0];
            float4 o;
            o.x = fmaxf(a0 + bb.x, 0.f);
            o.y = fmaxf(a1 + bb.y, 0.f);
            o.z = fmaxf(a2 + bb.z, 0.f);
            o.w = fmaxf(a3 + bb.w, 0.f);
            *(float4*)&x2s[(h * 64 + r) * 16 + c0] = o;
        }
    }
    __syncthreads();   // x2s complete

    // ---- A fragments (hi/lo split of 256*x) + publish xk (cz==0) ----
    const int col  = lane & 15;
    const int quad = lane >> 4;
    const int dims = (quad & 1) * 8;
    const int part = quad >> 1;
    f16x8 A[2];
    #pragma unroll
    for (int g = 0; g < 2; ++g) {
        const float* xp = &x2s[(wid * 32 + g * 16 + col) * 16 + dims];
        f16x8 hi, lo;
        #pragma unroll
        for (int j = 0; j < 8; ++j) {
            const float s = xp[j] * 256.0f;
            const _Float16 hh = (_Float16)s;
            hi[j] = hh;
            lo[j] = (_Float16)(s - (float)hh);
        }
        A[g] = part ? lo : hi;
    }
    if (cz == 0) {   // rescue path reads xk globally
        #pragma unroll
        for (int q = 0; q < 2; ++q) {
            const int e = q * 256 + t;
            ((float4*)&xk[((size_t)k * NROWS + row0) * DSUB])[e] = ((float4*)x2s)[e];
        }
    }
    // ---- local norms for this (k, cz): 1024 centroids ----
    #pragma unroll
    for (int q = 0; q < 4; ++q) {
        const int cl = q * 256 + t;
        const float4* cp = (const float4*)&ce[((size_t)k * NC + cz * 1024 + cl) * DSUB];
        float nn = 0.f;
        #pragma unroll
        for (int qq = 0; qq < 4; ++qq) {
            const float4 v = cp[qq];
            nn = fmaf(v.x, v.x, nn); nn = fmaf(v.y, v.y, nn);
            nn = fmaf(v.z, v.z, nn); nn = fmaf(v.w, v.w, nn);
        }
        cnL[cl] = nn;
    }

    // ---- scan (r13 proven core): 8 chunks x 8 tiles, convert B-frags from ce ----
    float m1[2][4], m2[2][4];
    int   idx[2][4];
    #pragma unroll
    for (int g = 0; g < 2; ++g)
        #pragma unroll
        for (int j = 0; j < 4; ++j) { m1[g][j] = 1e30f; m2[g][j] = 1e30f; idx[g][j] = 0; }

    for (int ch = 0; ch < 8; ++ch) {
        __syncthreads();                       // prev chunk consumed (1st iter: cnL/x2s phase done)
        #pragma unroll
        for (int q = 0; q < 2; ++q) {          // stage+convert 8 tiles (512 entries)
            const int e  = q * 256 + t;
            const int tl = e >> 6, le = e & 63;
            const int n  = (cz * 64 + ch * 8 + tl) * 16 + (le & 15);
            const float* cp = &ce[((size_t)k * NC + n) * DSUB + ((le >> 4) & 1) * 8];
            const float4 va = *(const float4*)cp;
            const float4 vb = *(const float4*)(cp + 4);
            const float sv[8] = {va.x, va.y, va.z, va.w, vb.x, vb.y, vb.z, vb.w};
            f16x8 hi, lo;
            #pragma unroll
            for (int j = 0; j < 8; ++j) {
                const float s = sv[j] * 16.0f;               // pow2 scale keeps lo normal
                const _Float16 hh = (_Float16)s;
                hi[j] = hh;
                lo[j] = (_Float16)(s - (float)hh);
            }
            cs[e] = (le >> 5) ? lo : hi;
        }
        __syncthreads();

        #pragma unroll 2
        for (int tt = 0; tt < 8; ++tt) {
            const f16x8 b1f = cs[tt * 64 + lane];
            const f16x8 b2f = cs[tt * 64 + (lane ^ 32)];  // part-flipped partner
            const float nrm = cnL[(ch * 8 + tt) * 16 + col];
            const f32x4 zz = {0.f, 0.f, 0.f, 0.f};
            f32x4 p0 = __builtin_amdgcn_mfma_f32_16x16x32_f16(A[0], b1f, zz, 0, 0, 0);
            p0       = __builtin_amdgcn_mfma_f32_16x16x32_f16(A[0], b2f, p0, 0, 0, 0);
            f32x4 p1 = __builtin_amdgcn_mfma_f32_16x16x32_f16(A[1], b1f, zz, 0, 0, 0);
            p1       = __builtin_amdgcn_mfma_f32_16x16x32_f16(A[1], b2f, p1, 0, 0, 0);
            const int c = ((cz * 64 + ch * 8 + tt) << 4) + col;
            #pragma unroll
            for (int j = 0; j < 4; ++j) {
                {
                    const float s = fmaf(p0[j], DOTSCALE, nrm);
                    const bool lt = s < m1[0][j];
                    m2[0][j] = __builtin_amdgcn_fmed3f(s, m1[0][j], m2[0][j]);
                    idx[0][j] = lt ? c : idx[0][j];
                    m1[0][j] = fminf(s, m1[0][j]);
                }
                {
                    const float s = fmaf(p1[j], DOTSCALE, nrm);
                    const bool lt = s < m1[1][j];
                    m2[1][j] = __builtin_amdgcn_fmed3f(s, m1[1][j], m2[1][j]);
                    idx[1][j] = lt ? c : idx[1][j];
                    m1[1][j] = fminf(s, m1[1][j]);
                }
            }
        }
    }

    // reduce across the 16 lanes of each quad
    #pragma unroll
    for (int off = 1; off < 16; off <<= 1) {
        #pragma unroll
        for (int g = 0; g < 2; ++g)
            #pragma unroll
            for (int j = 0; j < 4; ++j) {
                const float om1 = __shfl_xor(m1[g][j], off, 64);
                const float om2 = __shfl_xor(m2[g][j], off, 64);
                const int  oidx = __shfl_xor(idx[g][j], off, 64);
                const bool better = (om1 < m1[g][j]) ||
                                    (om1 == m1[g][j] && oidx < idx[g][j]);
                m2[g][j] = fminf(fminf(m2[g][j], om2), fmaxf(m1[g][j], om1));
                m1[g][j] = better ? om1 : m1[g][j];
                idx[g][j] = better ? oidx : idx[g][j];
            }
    }

    if (col == 0) {
        #pragma unroll
        for (int g = 0; g < 2; ++g)
            #pragma unroll
            for (int j = 0; j < 4; ++j) {
                const int row = row0 + wid * 32 + g * 16 + quad * 4 + j;
                unsigned u = __float_as_uint(m1[g][j]);
                u = (u & 0x80000000u) ? ~u : (u | 0x80000000u);      // order-preserving
                const unsigned short dh =
                    __half_as_ushort(__float2half(m2[g][j] - m1[g][j]));
                pk[((size_t)cz * NROWS + row) * KSUB + k] =
                    ((unsigned long long)u << 32) |
                    ((unsigned)dh << 16) | (unsigned)idx[g][j];
            }
    }

    // ---- last-arriver finish: merge + exact rescue + LUT output for these 128 rows ----
    __threadfence();                       // release pk / xk stores
    __syncthreads();
    if (t == 0) isLast = (atomicAdd(&done[bx], 1u) == 31u) ? 1 : 0;
    __syncthreads();
    if (!isLast) return;
    __threadfence();                       // acquire other blocks' stores

    if (t == 0) wcnt = 0;
    __syncthreads();

    #pragma unroll
    for (int i = 0; i < 4; ++i) {          // merge 4 splits; 1024 (row,k) pairs
        const int pr = i * 256 + t;
        const int row = row0 + (pr >> 3), kk = pr & 7;
        unsigned long long p[4];
        #pragma unroll
        for (int s = 0; s < 4; ++s)
            p[s] = pk[((size_t)s * NROWS + row) * KSUB + kk];
        unsigned long long w = p[0];
        #pragma unroll
        for (int s = 1; s < 4; ++s) w = p[s] < w ? p[s] : w;
        const unsigned uw = (unsigned)(w >> 32);
        const float m1w = __uint_as_float((uw & 0x80000000u) ? (uw ^ 0x80000000u) : ~uw);
        float m2g = m1w + (float)__ushort_as_half((unsigned short)((unsigned)w >> 16));
        #pragma unroll
        for (int s = 0; s < 4; ++s) {
            if (p[s] != w) {               // splits have disjoint idx ranges -> unique values
                const unsigned us = (unsigned)(p[s] >> 32);
                m2g = fminf(m2g, __uint_as_float(
                    (us & 0x80000000u) ? (us ^ 0x80000000u) : ~us));
            }
        }
        codes_s[pr] = (int)(w & 0xFFFFull);
        if (m2g - m1w < FB_TAU) wl_s[atomicAdd(&wcnt, 1)] = pr;
    }
    __syncthreads();

    {   // exact fp32 rescue, wave-per-item (norms recomputed inline, np-order chain)
        const int nit = wcnt;
        for (int i = wid; i < nit; i += 4) {
            const int pr = wl_s[i];
            const int row = row0 + (pr >> 3), kk = pr & 7;
            float xr[DSUB];
            {
                const float* xp = &xk[((size_t)kk * NROWS + row) * DSUB];
                #pragma unroll
                for (int q = 0; q < DSUB; q += 4) {
                    const float4 v = *(const float4*)&xp[q];
                    xr[q + 0] = -2.f * v.x; xr[q + 1] = -2.f * v.y;
                    xr[q + 2] = -2.f * v.z; xr[q + 3] = -2.f * v.w;
                }
            }
            float bm = 1e30f; int bi = NC;
            for (int c = lane; c < NC; c += 64) {
                const float4* cp = (const float4*)&ce[((size_t)kk * NC + c) * DSUB];
                const float4 v0 = cp[0], v1 = cp[1], v2 = cp[2], v3 = cp[3];
                float nn = 0.f;
                nn = fmaf(v0.x, v0.x, nn); nn = fmaf(v0.y, v0.y, nn);
                nn = fmaf(v0.z, v0.z, nn); nn = fmaf(v0.w, v0.w, nn);
                nn = fmaf(v1.x, v1.x, nn); nn = fmaf(v1.y, v1.y, nn);
                nn = fmaf(v1.z, v1.z, nn); nn = fmaf(v1.w, v1.w, nn);
                nn = fmaf(v2.x, v2.x, nn); nn = fmaf(v2.y, v2.y, nn);
                nn = fmaf(v2.z, v2.z, nn); nn = fmaf(v2.w, v2.w, nn);
                nn = fmaf(v3.x, v3.x, nn); nn = fmaf(v3.y, v3.y, nn);
                nn = fmaf(v3.z, v3.z, nn); nn = fmaf(v3.w, v3.w, nn);
                float s = nn;
                s = fmaf(xr[0],  v0.x, s); s = fmaf(xr[1],  v0.y, s);
                s = fmaf(xr[2],  v0.z, s); s = fmaf(xr[3],  v0.w, s);
                s = fmaf(xr[4],  v1.x, s); s = fmaf(xr[5],  v1.y, s);
                s = fmaf(xr[6],  v1.z, s); s = fmaf(xr[7],  v1.w, s);
                s = fmaf(xr[8],  v2.x, s); s = fmaf(xr[9],  v2.y, s);
                s = fmaf(xr[10], v2.z, s); s = fmaf(xr[11], v2.w, s);
                s = fmaf(xr[12], v3.x, s); s = fmaf(xr[13], v3.y, s);
                s = fmaf(xr[14], v3.z, s); s = fmaf(xr[15], v3.w, s);
                if (s < bm) { bm = s; bi = c; }
            }
            #pragma unroll
            for (int off = 1; off < 64; off <<= 1) {
                const float om = __shfl_xor(bm, off, 64);
                const int  oi = __shfl_xor(bi, off, 64);
                const bool better = (om < bm) || (om == bm && oi < bi);
                bm = better ? om : bm;
                bi = better ? oi : bi;
            }
            if (lane == 0) codes_s[pr] = bi;
        }
    }
    __syncthreads();

    #pragma unroll
    for (int i = 0; i < 3; ++i) {          // output: 128 rows x 6 = 768
        const int e = i * 256 + t;
        if (e < 128 * OUTD) {
            const int nl = e / OUTD;
            const int o = e - nl * OUTD;
            const int n = row0 + nl;
            float a = b3[o];
            #pragma unroll
            for (int kk = 0; kk < KSUB; ++kk) {
                const int code = codes_s[nl * KSUB + kk];
                const float* cp = &ce[((size_t)kk * NC + code) * DSUB];
                const float* wp = &W3[(kk * DSUB) * OUTD + o];
                #pragma unroll
                for (int d = 0; d < DSUB; ++d)
                    a = fmaf(cp[d], wp[d * OUTD], a);
            }
            out[n * OUTD + o] = a;
        }
    }
}

extern "C" void kernel_launch(void* const* d_in, const int* in_sizes, int n_in,
                              void* d_out, int out_size, void* d_ws, size_t ws_size,
                              hipStream_t stream)
{
    const float* z  = (const float*)d_in[0];
    const float* W1 = (const float*)d_in[1];
    const float* b1 = (const float*)d_in[2];
    const float* W2 = (const float*)d_in[3];
    const float* b2 = (const float*)d_in[4];
    const float* ce = (const float*)d_in[5];
    const float* W3 = (const float*)d_in[6];
    const float* b3 = (const float*)d_in[7];

    char* ws = (char*)d_ws;
    float* xk = (float*)(ws + XK_OFF);
    unsigned long long* pk = (unsigned long long*)(ws + PK_OFF);
    unsigned int* done = (unsigned int*)(ws + DN_OFF);

    hipMemsetAsync(done, 0, 64 * sizeof(unsigned int), stream);
    hipLaunchKernelGGL(fused_kernel, dim3(64, 8, 4), dim3(256), 0, stream,
                       z, W1, b1, W2, b2, ce, W3, b3,
                       xk, pk, done, (float*)d_out);
}

// Round 17
// 177.439 us; speedup vs baseline: 2.2116x; 2.2116x over previous
//
#include <hip/hip_runtime.h>
#include <hip/hip_fp16.h>
#include <stdint.h>

#define NROWS 8192   // B*S
#define HDIM  128
#define KSUB  8
#define NC    4096
#define DSUB  16
#define OUTD  6

#define FB_TAU 6e-5f                // fallback margin; split-fp16 distance error bound ~1.5e-5

typedef _Float16 f16x8 __attribute__((ext_vector_type(8)));
typedef float    f32x4 __attribute__((ext_vector_type(4)));

// ws layout (bytes): total 8,519,680
#define XK_OFF 0u            // xk:   [KSUB][NROWS][DSUB] fp32, 4 MiB
#define CN_OFF 4194304u      // cnorm:[KSUB][NC] fp32, 128 KiB
#define B1_OFF 4325376u      // B1S:  [KSUB][256 tiles][64 lanes] f16x8 (NEGATED -16c), 2 MiB
#define PK_OFF 6422528u      // pk:   [4 splits][NROWS][KSUB] u64, 2 MiB

// ---------------- Kernel 1: prep = MLP + cnorm + bprep (512 blocks, 16 rows each) ------
__global__ __launch_bounds__(256) void prep_kernel(
    const float* __restrict__ z, const float* __restrict__ W1, const float* __restrict__ b1,
    const float* __restrict__ W2, const float* __restrict__ b2,
    const float* __restrict__ ce,
    float* __restrict__ xk, float* __restrict__ cnorm, f16x8* __restrict__ B1S)
{
    __shared__ float h1s[16 * HDIM];    // 8 KiB
    __shared__ float w2s[HDIM * HDIM];  // 64 KiB
    const int t = threadIdx.x;
    const int row0 = blockIdx.x * 16;

    // ---- bprep: hi/lo split of (-16*c). With A = 256x and C-init = 2048*nrm the
    // chained MFMA emits 2048*(nrm - 2*dot) directly (pow2-exact; r11-verified algebra).
    {
        const int e = blockIdx.x * 256 + t;
        const int k    = e >> 14;
        const int tile = (e >> 6) & 255;
        const int lane = e & 63;
        const int col  = lane & 15;
        const int quad = lane >> 4;
        const int dims = (quad & 1) * 8;
        const int part = quad >> 1;                      // 0: hi half of K, 1: lo half
        const int n = tile * 16 + col;
        const float* cp = &ce[((size_t)k * NC + n) * DSUB + dims];
        f16x8 hi, lo;
        #pragma unroll
        for (int j = 0; j < 8; ++j) {
            const float s = cp[j] * -16.0f;              // pow2 scale (negated), lo stays normal
            const _Float16 h = (_Float16)s;
            hi[j] = h;
            lo[j] = (_Float16)(s - (float)h);
        }
        B1S[e] = part ? lo : hi;
    }

    // centroid norms (first 128 blocks cover KSUB*NC = 32768 centroids)
    if (blockIdx.x < (KSUB * NC) / 256) {
        const int g = blockIdx.x * 256 + t;
        const float4* cp = (const float4*)&ce[(size_t)g * DSUB];
        float nn = 0.f;
        #pragma unroll
        for (int q = 0; q < 4; ++q) {
            const float4 v = cp[q];
            nn = fmaf(v.x, v.x, nn); nn = fmaf(v.y, v.y, nn);
            nn = fmaf(v.z, v.z, nn); nn = fmaf(v.w, v.w, nn);
        }
        cnorm[g] = nn;
    }

    // stage W2 (coalesced)
    {
        const float4* g4 = (const float4*)W2;
        float4* s4 = (float4*)w2s;
        #pragma unroll
        for (int q = 0; q < 16; ++q) s4[t + q * 256] = g4[t + q * 256];
    }

    // phase A: h1 = relu(z @ W1 + b1) into LDS (16x128)
    #pragma unroll
    for (int e = 0; e < 8; ++e) {
        const int idx = e * 256 + t;
        const int r = idx >> 7, j = idx & 127;
        const int n = row0 + r;
        float acc = b1[j];
        acc = fmaf(z[n * 3 + 0], W1[0 * HDIM + j], acc);
        acc = fmaf(z[n * 3 + 1], W1[1 * HDIM + j], acc);
        acc = fmaf(z[n * 3 + 2], W1[2 * HDIM + j], acc);
        h1s[idx] = fmaxf(acc, 0.f);
    }
    __syncthreads();

    // phase B: 2 rows x 4 cols per thread (same per-output fma chain as before)
    const int c4 = (t & 31) * 4;
    const int r2 = (t >> 5) * 2;
    float acc[2][4];
    #pragma unroll
    for (int a = 0; a < 2; ++a)
        #pragma unroll
        for (int b = 0; b < 4; ++b) acc[a][b] = 0.f;

    for (int k4 = 0; k4 < HDIM; k4 += 4) {
        float hh[2][4], ww[4][4];
        #pragma unroll
        for (int q = 0; q < 2; ++q) {
            const float4 v = *(const float4*)&h1s[(r2 + q) * HDIM + k4];
            hh[q][0] = v.x; hh[q][1] = v.y; hh[q][2] = v.z; hh[q][3] = v.w;
        }
        #pragma unroll
        for (int p = 0; p < 4; ++p) {
            const float4 v = *(const float4*)&w2s[(k4 + p) * HDIM + c4];
            ww[p][0] = v.x; ww[p][1] = v.y; ww[p][2] = v.z; ww[p][3] = v.w;
        }
        #pragma unroll
        for (int q = 0; q < 2; ++q)
            #pragma unroll
            for (int p = 0; p < 4; ++p) {
                acc[q][0] = fmaf(hh[q][p], ww[p][0], acc[q][0]);
                acc[q][1] = fmaf(hh[q][p], ww[p][1], acc[q][1]);
                acc[q][2] = fmaf(hh[q][p], ww[p][2], acc[q][2]);
                acc[q][3] = fmaf(hh[q][p], ww[p][3], acc[q][3]);
            }
    }

    const float4 bb = *(const float4*)&b2[c4];
    const int kk = c4 >> 4;
    const int dd = c4 & 15;
    #pragma unroll
    for (int q = 0; q < 2; ++q) {
        float4 o;
        o.x = fmaxf(acc[q][0] + bb.x, 0.f);
        o.y = fmaxf(acc[q][1] + bb.y, 0.f);
        o.z = fmaxf(acc[q][2] + bb.z, 0.f);
        o.w = fmaxf(acc[q][3] + bb.w, 0.f);
        *(float4*)&xk[((size_t)kk * NROWS + (row0 + r2 + q)) * DSUB + dd] = o;
    }
}

// ---------------- Kernel 2: MFMA 16x16 argmin, barrier-free global stream ----------------
// r9-r15 plateau: every LDS-staged variant sits at 75-82 us regardless of
// occupancy/op-count/shape -> the chunk-barrier pacing is the invariant.
// This version: 64 rows/wave, B tiles streamed per-wave from global (b2 =
// same 1 KB line lane-permuted -> L1 hit), prefetch-1 in regs, ONE barrier
// total. grid (32, 8 k, 4 cz) = 1024 blocks x 4 waves = 16 waves/CU.
__global__ __launch_bounds__(256, 4) void argmin_kernel(
    const float* __restrict__ xk, const f16x8* __restrict__ B1S,
    const float* __restrict__ cnorm, unsigned long long* __restrict__ pk)
{
    __shared__ float cnL[1024];     // 4 KiB = norms * 2048 for this (k, cz)
    const int t = threadIdx.x;
    const int lane = t & 63;
    const int wid  = t >> 6;
    const int k  = blockIdx.y;                 // 0..7
    const int cz = blockIdx.z;                 // 0..3
    const int rb = blockIdx.x * 4 + wid;       // 0..127 (64-row block)
    const int col  = lane & 15;
    const int quad = lane >> 4;
    const int dims = (quad & 1) * 8;
    const int part = quad >> 1;

    // stage the 1024 norms of this centroid split, pre-scaled by 2048 (pow2-exact)
    {
        const float* cnp0 = &cnorm[k * NC + cz * 1024];
        #pragma unroll
        for (int q = 0; q < 4; ++q) cnL[t + q * 256] = cnp0[t + q * 256] * 2048.0f;
    }

    // A fragments for 4 groups of 16 rows (hi/lo split of 256*x, exact)
    f16x8 A[4];
    #pragma unroll
    for (int g = 0; g < 4; ++g) {
        const int row = rb * 64 + g * 16 + col;
        const float* xp = &xk[((size_t)k * NROWS + row) * DSUB + dims];
        f16x8 hi, lo;
        #pragma unroll
        for (int j = 0; j < 8; ++j) {
            const float s = xp[j] * 256.0f;
            const _Float16 h = (_Float16)s;
            hi[j] = h;
            lo[j] = (_Float16)(s - (float)h);
        }
        A[g] = part ? lo : hi;
    }

    float m1[4][4], m2[4][4];
    int   idx[4][4];   // tile-id within split (0..63)
    #pragma unroll
    for (int g = 0; g < 4; ++g)
        #pragma unroll
        for (int j = 0; j < 4; ++j) { m1[g][j] = 1e30f; m2[g][j] = 1e30f; idx[g][j] = 0; }

    __syncthreads();   // cnL ready -- the only barrier in this kernel

    const f16x8* gB = &B1S[((size_t)k * 256 + cz * 64) * 64];
    const int l2 = lane ^ 32;                  // part-flipped partner (same 1 KB line)

    f16x8 ca = gB[lane], cb = gB[l2];          // prefetch tile 0

    #pragma unroll 2
    for (int tt = 0; tt < 64; ++tt) {
        const f16x8 ba = ca, bb = cb;
        if (tt + 1 < 64) {                     // prefetch next tile (overlaps compute)
            ca = gB[(tt + 1) * 64 + lane];
            cb = gB[(tt + 1) * 64 + l2];
        }
        const float nrmS = cnL[tt * 16 + col]; // 2048*nrm, broadcast
        const f32x4 cn4 = {nrmS, nrmS, nrmS, nrmS};
        #pragma unroll
        for (int g = 0; g < 4; ++g) {
            f32x4 p = __builtin_amdgcn_mfma_f32_16x16x32_f16(A[g], ba, cn4, 0, 0, 0);
            p       = __builtin_amdgcn_mfma_f32_16x16x32_f16(A[g], bb, p,   0, 0, 0);
            // p[j] = 2048*(nrm - 2*dot)  -- scaled distance, order-preserved
            #pragma unroll
            for (int j = 0; j < 4; ++j) {
                const float s = p[j];
                const bool lt = s < m1[g][j];
                m2[g][j] = __builtin_amdgcn_fmed3f(s, m1[g][j], m2[g][j]);
                idx[g][j] = lt ? tt : idx[g][j];
                m1[g][j] = fminf(s, m1[g][j]);
            }
        }
    }

    // rebuild full centroid index before cross-lane reduce (idx order must match c order)
    #pragma unroll
    for (int g = 0; g < 4; ++g)
        #pragma unroll
        for (int j = 0; j < 4; ++j)
            idx[g][j] = ((cz * 64 + idx[g][j]) << 4) + col;

    // reduce across the 16 lanes of each quad
    #pragma unroll
    for (int off = 1; off < 16; off <<= 1) {
        #pragma unroll
        for (int g = 0; g < 4; ++g)
            #pragma unroll
            for (int j = 0; j < 4; ++j) {
                const float om1 = __shfl_xor(m1[g][j], off, 64);
                const float om2 = __shfl_xor(m2[g][j], off, 64);
                const int  oidx = __shfl_xor(idx[g][j], off, 64);
                const bool better = (om1 < m1[g][j]) ||
                                    (om1 == m1[g][j] && oidx < idx[g][j]);
                m2[g][j] = fminf(fminf(m2[g][j], om2), fmaxf(m1[g][j], om1));
                m1[g][j] = better ? om1 : m1[g][j];
                idx[g][j] = better ? oidx : idx[g][j];
            }
    }

    if (col == 0) {   // lanes 0,16,32,48 hold final results for their 4 rows each
        #pragma unroll
        for (int g = 0; g < 4; ++g)
            #pragma unroll
            for (int j = 0; j < 4; ++j) {
                const int row = rb * 64 + g * 16 + quad * 4 + j;
                const float m1t = m1[g][j] * (1.0f / 2048.0f);   // unscale (pow2-exact)
                unsigned u = __float_as_uint(m1t);
                u = (u & 0x80000000u) ? ~u : (u | 0x80000000u);      // order-preserving
                const unsigned short dh = __half_as_ushort(
                    __float2half((m2[g][j] - m1[g][j]) * (1.0f / 2048.0f)));
                pk[((size_t)cz * NROWS + row) * KSUB + k] =
                    ((unsigned long long)u << 32) |
                    ((unsigned)dh << 16) | (unsigned)idx[g][j];
            }
    }
}

// ---------------- Kernel 3: finish = merge 4 splits + exact rescue + LUT output --------
__global__ __launch_bounds__(256) void finish_kernel(
    const float* __restrict__ xk, const float* __restrict__ ce,
    const float* __restrict__ cnorm, const unsigned long long* __restrict__ pk,
    const float* __restrict__ W3, const float* __restrict__ b3,
    float* __restrict__ out)
{
    __shared__ int codes_s[256];
    __shared__ int wl_s[256];
    __shared__ int wcnt;
    const int t = threadIdx.x;
    const int row0 = blockIdx.x * 32;
    if (t == 0) wcnt = 0;
    __syncthreads();

    // merge 4 splits for (row, k) = (row0 + t>>3, t&7)
    {
        const int row = row0 + (t >> 3);
        const int k = t & 7;
        unsigned long long p[4];
        #pragma unroll
        for (int s = 0; s < 4; ++s)
            p[s] = pk[((size_t)s * NROWS + row) * KSUB + k];
        unsigned long long w = p[0];
        #pragma unroll
        for (int s = 1; s < 4; ++s) w = p[s] < w ? p[s] : w;
        const unsigned uw = (unsigned)(w >> 32);
        const float m1w = __uint_as_float((uw & 0x80000000u) ? (uw ^ 0x80000000u) : ~uw);
        float m2g = m1w + (float)__ushort_as_half((unsigned short)((unsigned)w >> 16));
        #pragma unroll
        for (int s = 0; s < 4; ++s) {
            if (p[s] != w) {   // splits have disjoint idx ranges -> pk values unique
                const unsigned us = (unsigned)(p[s] >> 32);
                m2g = fminf(m2g, __uint_as_float(
                    (us & 0x80000000u) ? (us ^ 0x80000000u) : ~us));
            }
        }
        codes_s[t] = (int)(w & 0xFFFFull);
        if (m2g - m1w < FB_TAU) {      // near-tie: exact fp32 rescan needed
            const int slot = atomicAdd(&wcnt, 1);
            wl_s[slot] = t;
        }
    }
    __syncthreads();

    // exact fp32 rescue, wave-per-item over the block-local worklist
    {
        const int lane = t & 63;
        const int wid = t >> 6;
        const int nitems = wcnt;
        for (int i = wid; i < nitems; i += 4) {
            const int wg = wl_s[i];
            const int row = row0 + (wg >> 3), k = wg & 7;
            float xr[DSUB];
            {
                const float* xp = &xk[((size_t)k * NROWS + row) * DSUB];
                #pragma unroll
                for (int q = 0; q < DSUB; q += 4) {
                    const float4 v = *(const float4*)&xp[q];
                    xr[q + 0] = -2.f * v.x; xr[q + 1] = -2.f * v.y;
                    xr[q + 2] = -2.f * v.z; xr[q + 3] = -2.f * v.w;
                }
            }
            float bm = 1e30f; int bi = NC;
            for (int c = lane; c < NC; c += 64) {
                const float* cp = &ce[((size_t)k * NC + c) * DSUB];
                float s = cnorm[k * NC + c];
                #pragma unroll
                for (int d = 0; d < DSUB; ++d) s = fmaf(xr[d], cp[d], s);
                if (s < bm) { bm = s; bi = c; }
            }
            #pragma unroll
            for (int off = 1; off < 64; off <<= 1) {
                const float om = __shfl_xor(bm, off, 64);
                const int  oi = __shfl_xor(bi, off, 64);
                const bool better = (om < bm) || (om == bm && oi < bi);
                bm = better ? om : bm;
                bi = better ? oi : bi;
            }
            if (lane == 0) codes_s[wg] = bi;
        }
    }
    __syncthreads();

    // output: 32 rows x 6 = 192 outputs
    if (t < 32 * OUTD) {
        const int nl = t / OUTD;
        const int o = t - nl * OUTD;
        const int n = row0 + nl;
        float acc = b3[o];
        #pragma unroll
        for (int k = 0; k < KSUB; ++k) {
            const int code = codes_s[nl * KSUB + k];
            const float* cp = &ce[((size_t)k * NC + code) * DSUB];
            const float* wp = &W3[(k * DSUB) * OUTD + o];
            #pragma unroll
            for (int d = 0; d < DSUB; ++d)
                acc = fmaf(cp[d], wp[d * OUTD], acc);
        }
        out[n * OUTD + o] = acc;
    }
}

extern "C" void kernel_launch(void* const* d_in, const int* in_sizes, int n_in,
                              void* d_out, int out_size, void* d_ws, size_t ws_size,
                              hipStream_t stream)
{
    const float* z  = (const float*)d_in[0];
    const float* W1 = (const float*)d_in[1];
    const float* b1 = (const float*)d_in[2];
    const float* W2 = (const float*)d_in[3];
    const float* b2 = (const float*)d_in[4];
    const float* ce = (const float*)d_in[5];
    const float* W3 = (const float*)d_in[6];
    const float* b3 = (const float*)d_in[7];

    char* ws = (char*)d_ws;
    float* xk    = (float*)(ws + XK_OFF);
    float* cnorm = (float*)(ws + CN_OFF);
    f16x8* B1S   = (f16x8*)(ws + B1_OFF);
    unsigned long long* pk = (unsigned long long*)(ws + PK_OFF);

    hipLaunchKernelGGL(prep_kernel, dim3(512), dim3(256), 0, stream,
                       z, W1, b1, W2, b2, ce, xk, cnorm, B1S);
    hipLaunchKernelGGL(argmin_kernel, dim3(32, 8, 4), dim3(256), 0, stream,
                       xk, B1S, cnorm, pk);
    hipLaunchKernelGGL(finish_kernel, dim3(256), dim3(256), 0, stream,
                       xk, ce, cnorm, pk, W3, b3, (float*)d_out);
}